// Round 10
// baseline (319.081 us; speedup 1.0000x reference)
//
#include <hip/hip_runtime.h>
#include <math.h>

// DigitCaps dynamic routing. B=512, I=1152, K=8, C=10, D=16, 3 iters.
//
// R5 structure: materialize bf16 u_hat (189 MB) in ws; each routing pass
// streams it once; softmax fully in-register.
// R7: forcing launch_bounds below natural need -> spills. Keep (256,4).
// R10: i-split alone doubled s0 atomics (WRITE 226->268 MB).
// R11: source-level ILP gets compiled away.
// R12: b-pairs double W_t loads per FMA: regressed. Compute-per-load matters.
// R13: c-lane route family (>=80 VGPR, 4 waves/SIMD) loses to cd-quad TLP.
// R14 WIN (311us): route6 = cd-quad route (VGPR ~20) + grid 2048 + rcp.
// R15 WIN (302us): producer LDS cross-wave reduce decoupled atomics from
//   i-splitting (WRITE 226->206 MB); producer 143->128us. Still latency-bound:
//   8 W_t loads feed only 128 FMA per ii.
// R16 (this round):
//   - producer b-OCT: 8 b/wave -> 256 FMA per 8 loads (2x compute-per-load),
//     W_t L2 traffic halves (755->378 MB). 64 bq x 64 ch = 4096 waves =
//     1024 blocks, one round at 4-wave tier (VGPR ~100 < 128). LDS reduce kept.
//   - route7: 4-wide (4 rows/iter, 4 loads in flight, 4 interleaved shfl/exp
//     chains), inline bf16 unpack keeps natural VGPR ~45 <= 64 -> 8-wave tier.

#define UHQ 40          // ushort4 quads per (b,i) row (160 bf16 elems)

__device__ __forceinline__ float dot8(const float4 w0, const float4 w1,
                                      const float4 ua, const float4 ub) {
    return w0.x*ua.x + w0.y*ua.y + w0.z*ua.z + w0.w*ua.w
         + w1.x*ub.x + w1.y*ub.y + w1.z*ub.z + w1.w*ub.w;
}

__device__ __forceinline__ unsigned short bf16_rn(float x) {
    unsigned u = __float_as_uint(x);
    u += 0x7FFFu + ((u >> 16) & 1u);
    return (unsigned short)(u >> 16);
}
__device__ __forceinline__ float bf16_to_f(unsigned short h) {
    return __uint_as_float(((unsigned)h) << 16);
}

// ---------------- W transpose: W[i][c][d][k] -> W_t[i][j][q] (float4 units) ----------------
__global__ void transpose_W(const float4* __restrict__ W4, float4* __restrict__ Wt4)
{
    int tid = blockIdx.x * 256 + threadIdx.x;
    if (tid >= 1152 * 320) return;
    int i = tid / 320, r = tid - i * 320;
    int q = r >> 3, j = r & 7;
    Wt4[i * 320 + j * 40 + q] = W4[tid];   // read coalesced, scatter within 5 KB row
}

// ---------------- Producer b-OCT: u_hat bf16 + fused pass-0 sum, LDS reduce ----------------
// 8 b per wave: per ii, 8 W_t loads feed 256 FMA (was 128) -> latency hidden
// by compute, and total W_t L2 reads halve. 64 bq x 64 ch (18 i) = 4096 waves
// = 1024 blocks = one uniform round. Block's 4 waves share the b-oct: waves
// 1-3 park acc in LDS (15.4 KB), wave 0 alone issues atomics.
__global__ __launch_bounds__(256, 4)
void produce_uhat_t(const float* __restrict__ u, const float* __restrict__ Wt,
                    unsigned short* __restrict__ uhat_h, float* __restrict__ s0)
{
    const int t = threadIdx.x, lane = t & 63, wv = t >> 6;
    const int gid = blockIdx.x * 4 + wv;        // 0..4095
    const int bq  = gid >> 6;                   // 0..63 (same for block's 4 waves)
    const int ch  = gid & 63;                   // 0..63
    const int b0  = bq * 8;
    const int i0  = ch * 18;
    const int q   = lane;
    const bool act = (q < UHQ);

    __shared__ float4 red[960];           // 3 waves x 40 lanes x 8 float4 = 15360 B

    float4 acc[8];
    #pragma unroll
    for (int bb = 0; bb < 8; ++bb) acc[bb] = make_float4(0.f, 0.f, 0.f, 0.f);

    for (int ii = 0; ii < 18; ++ii) {
        const int i = i0 + ii;
        float4 w4[8];
        if (act) {
            const float4* wb = (const float4*)(Wt + (size_t)i * 1280);
            #pragma unroll
            for (int j = 0; j < 8; ++j) w4[j] = wb[j * 40 + q];   // 640 B contiguous
        }
        #pragma unroll
        for (int bb = 0; bb < 8; ++bb) {
            const int b = b0 + bb;
            const float4* up = (const float4*)(u + ((size_t)b * 1152 + i) * 8);
            const float4 ua = up[0], ub = up[1];   // wave-uniform broadcast
            if (act) {
                float4 uh;
                uh.x = dot8(w4[0], w4[1], ua, ub);
                uh.y = dot8(w4[2], w4[3], ua, ub);
                uh.z = dot8(w4[4], w4[5], ua, ub);
                uh.w = dot8(w4[6], w4[7], ua, ub);
                acc[bb].x += uh.x; acc[bb].y += uh.y;
                acc[bb].z += uh.z; acc[bb].w += uh.w;
                ushort4 h;
                h.x = bf16_rn(uh.x); h.y = bf16_rn(uh.y);
                h.z = bf16_rn(uh.z); h.w = bf16_rn(uh.w);
                ((ushort4*)uhat_h)[((size_t)b * 1152 + i) * UHQ + q] = h;
            }
        }
    }

    // cross-wave reduction of the pass-0 partial sums
    if (wv > 0 && act) {
        float4* rp = red + ((wv - 1) * 40 + q) * 8;
        #pragma unroll
        for (int bb = 0; bb < 8; ++bb) rp[bb] = acc[bb];
    }
    __syncthreads();
    if (wv == 0 && act) {
        #pragma unroll
        for (int w = 0; w < 3; ++w) {
            const float4* rp = red + (w * 40 + q) * 8;
            #pragma unroll
            for (int bb = 0; bb < 8; ++bb) {
                const float4 r = rp[bb];
                acc[bb].x += r.x; acc[bb].y += r.y;
                acc[bb].z += r.z; acc[bb].w += r.w;
            }
        }
#if defined(__HIP_DEVICE_COMPILE__)
        #pragma unroll
        for (int bb = 0; bb < 8; ++bb) {
            float* sp = s0 + (size_t)(b0 + bb) * 160 + q * 4;
            unsafeAtomicAdd(sp + 0, acc[bb].x);
            unsafeAtomicAdd(sp + 1, acc[bb].y);
            unsafeAtomicAdd(sp + 2, acc[bb].z);
            unsafeAtomicAdd(sp + 3, acc[bb].w);
        }
#endif
    }
}

// ---------------- Producer fallback (divergent W, no W_t buffer; R9 geometry) ----------------
__global__ __launch_bounds__(256, 4)
void produce_uhat_div(const float* __restrict__ u, const float* __restrict__ W,
                      unsigned short* __restrict__ uhat_h, float* __restrict__ s0)
{
    const int t = threadIdx.x, lane = t & 63, wv = t >> 6;
    const int gid = blockIdx.x * 4 + wv;
    const int bq  = gid / 32;
    const int ch  = gid - bq * 32;
    const int b0  = bq * 4;
    const int i0  = ch * 36;
    const int q   = lane;
    const bool act = (q < UHQ);

    float4 acc[4];
    #pragma unroll
    for (int bb = 0; bb < 4; ++bb) acc[bb] = make_float4(0.f, 0.f, 0.f, 0.f);

    for (int ii = 0; ii < 36; ++ii) {
        const int i = i0 + ii;
        float4 w4[8];
        if (act) {
            const float4* wp = (const float4*)(W + (size_t)i * 1280 + q * 32);
            #pragma unroll
            for (int j = 0; j < 8; ++j) w4[j] = wp[j];
        }
        #pragma unroll
        for (int bb = 0; bb < 4; ++bb) {
            const int b = b0 + bb;
            const float4* up = (const float4*)(u + ((size_t)b * 1152 + i) * 8);
            const float4 ua = up[0], ub = up[1];
            if (act) {
                float4 uh;
                uh.x = dot8(w4[0], w4[1], ua, ub);
                uh.y = dot8(w4[2], w4[3], ua, ub);
                uh.z = dot8(w4[4], w4[5], ua, ub);
                uh.w = dot8(w4[6], w4[7], ua, ub);
                acc[bb].x += uh.x; acc[bb].y += uh.y;
                acc[bb].z += uh.z; acc[bb].w += uh.w;
                ushort4 h;
                h.x = bf16_rn(uh.x); h.y = bf16_rn(uh.y);
                h.z = bf16_rn(uh.z); h.w = bf16_rn(uh.w);
                ((ushort4*)uhat_h)[((size_t)b * 1152 + i) * UHQ + q] = h;
            }
        }
    }
    if (act) {
#if defined(__HIP_DEVICE_COMPILE__)
        #pragma unroll
        for (int bb = 0; bb < 4; ++bb) {
            float* sp = s0 + (size_t)(b0 + bb) * 160 + q * 4;
            unsafeAtomicAdd(sp + 0, acc[bb].x);
            unsafeAtomicAdd(sp + 1, acc[bb].y);
            unsafeAtomicAdd(sp + 2, acc[bb].z);
            unsafeAtomicAdd(sp + 3, acc[bb].w);
        }
#endif
    }
}

// ---------------- Routing pass v7: cd-quad 4-wide, inline unpack, 8 waves/SIMD ----------------
// Wave owns (b, i-chunk); lane q = cd-quad. 4 rows per iteration: 4 loads in
// flight, 4 interleaved shfl/exp chains. bf16 words unpacked inline (h[4]=8
// VGPR, no staging arrays) -> natural VGPR ~45 stays in the 8-wave tier.
// Grid 2048 = 8 blocks/CU, one uniform round. (256,4): never force allocator.
template <int PASS>
__global__ __launch_bounds__(256, 4)
void route7(const unsigned short* __restrict__ uhat_h,
            const float* __restrict__ v0g, const float* __restrict__ v1g,
            float* __restrict__ sg)
{
    const int t = threadIdx.x, lane = t & 63, wv = t >> 6;
    const int gid = blockIdx.x * 4 + wv;
    const int b   = gid >> 4;             // 0..511
    const int ch  = gid & 15;             // 0..15
    const int i0  = ch * 72;
    const int q   = lane;
    const bool act = (q < UHQ);

    float4 va = make_float4(0.f, 0.f, 0.f, 0.f);
    if (act) {
        va = ((const float4*)v0g)[(size_t)b * UHQ + q];
        if (PASS == 2) {
            const float4 vb = ((const float4*)v1g)[(size_t)b * UHQ + q];
            va.x += vb.x; va.y += vb.y; va.z += vb.z; va.w += vb.w;
        }
    }
    float4 sacc = make_float4(0.f, 0.f, 0.f, 0.f);

    const ushort4* up = (const ushort4*)uhat_h;

    for (int ii = 0; ii < 72; ii += 4) {
        const size_t qi = ((size_t)b * 1152 + i0 + ii) * UHQ + q;
        ushort4 h[4];
        #pragma unroll
        for (int k = 0; k < 4; ++k) h[k] = make_ushort4(0, 0, 0, 0);
        if (act) {
            #pragma unroll
            for (int k = 0; k < 4; ++k) h[k] = up[qi + (size_t)k * UHQ];
        }
        // per-c logit: 4-lane segmented reduction, 4 independent chains
        float p[4];
        #pragma unroll
        for (int k = 0; k < 4; ++k)
            p[k] = bf16_to_f(h[k].x)*va.x + bf16_to_f(h[k].y)*va.y
                 + bf16_to_f(h[k].z)*va.z + bf16_to_f(h[k].w)*va.w;
        #pragma unroll
        for (int k = 0; k < 4; ++k) p[k] += __shfl_xor(p[k], 1);
        #pragma unroll
        for (int k = 0; k < 4; ++k) p[k] += __shfl_xor(p[k], 2);
        // softmax, no max-subtraction (|logit| < ~0.5); mask inactive lanes
        float e[4], s[4];
        #pragma unroll
        for (int k = 0; k < 4; ++k) e[k] = act ? __expf(p[k]) : 0.0f;
        #pragma unroll
        for (int k = 0; k < 4; ++k) s[k] = e[k];
        // xor-butterfly strides 4..32: every lane gets the 10-class sum
        #pragma unroll
        for (int k = 0; k < 4; ++k) s[k] += __shfl_xor(s[k], 4);
        #pragma unroll
        for (int k = 0; k < 4; ++k) s[k] += __shfl_xor(s[k], 8);
        #pragma unroll
        for (int k = 0; k < 4; ++k) s[k] += __shfl_xor(s[k], 16);
        #pragma unroll
        for (int k = 0; k < 4; ++k) s[k] += __shfl_xor(s[k], 32);
        #pragma unroll
        for (int k = 0; k < 4; ++k) {
            const float c = e[k] * __builtin_amdgcn_rcpf(s[k]);
            sacc.x += c * bf16_to_f(h[k].x);
            sacc.y += c * bf16_to_f(h[k].y);
            sacc.z += c * bf16_to_f(h[k].z);
            sacc.w += c * bf16_to_f(h[k].w);
        }
    }
    if (act) {
#if defined(__HIP_DEVICE_COMPILE__)
        float* sp = sg + (size_t)b * 160 + q * 4;
        unsafeAtomicAdd(sp + 0, sacc.x);
        unsafeAtomicAdd(sp + 1, sacc.y);
        unsafeAtomicAdd(sp + 2, sacc.z);
        unsafeAtomicAdd(sp + 3, sacc.w);
#endif
    }
}

// ---------------- squash with pre-scale ----------------
__global__ void squash_scale(const float* __restrict__ s, float* __restrict__ vout,
                             float scale)
{
    int r = blockIdx.x * 256 + threadIdx.x;
    if (r >= 512 * 10) return;
    const float* sp = s + (size_t)r * 16;
    float sv[16];
    float ns = 0.0f;
    #pragma unroll
    for (int d = 0; d < 16; ++d) {
        float x = sp[d] * scale;
        sv[d] = x;
        ns += x * x;
    }
    float sc = ns / ((1.0f + ns) * (sqrtf(ns) + 1e-8f));
    float* o = vout + (size_t)r * 16;
    #pragma unroll
    for (int d = 0; d < 16; ++d) o[d] = sv[d] * sc;
}

// ---------------- tiny-ws fallback (R3-style): thread owns (b,c) ----------------
template <int PASS>
__global__ __launch_bounds__(256, 4)
void pass_fb(const float* __restrict__ u, const float* __restrict__ W,
             const float* __restrict__ v0g, const float* __restrict__ v1g,
             float* __restrict__ s_atomic)
{
    const int t    = threadIdx.x;
    const int lane = t & 63;
    const int wv   = t >> 6;
    const int bsub = lane / 10;
    const int c    = lane - bsub * 10;
    const bool lane_ok = (bsub < 6);
    const int b    = blockIdx.y * 24 + wv * 6 + bsub;
    const bool valid = lane_ok && (b < 512);
    const int bc   = valid ? b : 511;
    const int base = lane_ok ? bsub * 10 : 0;
    const int i0   = blockIdx.x * 24;

    float v[16];
    #pragma unroll
    for (int d = 0; d < 16; ++d) v[d] = 0.0f;
    if (PASS >= 1) {
        const float* vp = v0g + ((size_t)bc * 10 + c) * 16;
        #pragma unroll
        for (int d = 0; d < 16; ++d) v[d] = vp[d];
        if (PASS >= 2) {
            const float* vq = v1g + ((size_t)bc * 10 + c) * 16;
            #pragma unroll
            for (int d = 0; d < 16; ++d) v[d] += vq[d];
        }
    }

    float s_acc[16];
    #pragma unroll
    for (int d = 0; d < 16; ++d) s_acc[d] = 0.0f;

    for (int ii = 0; ii < 24; ++ii) {
        const int i = i0 + ii;
        const float4* up = (const float4*)(u + ((size_t)bc * 1152 + i) * 8);
        const float4 ua = up[0];
        const float4 ub = up[1];
        const float* Wp = W + ((size_t)i * 10 + c) * 128;

        float h[16];
        #pragma unroll
        for (int d = 0; d < 16; ++d) {
            const float4* wp = (const float4*)(Wp + d * 8);
            h[d] = dot8(wp[0], wp[1], ua, ub);
        }

        if (PASS == 0) {
            #pragma unroll
            for (int d = 0; d < 16; ++d) s_acc[d] += h[d];
        } else {
            float lg = 0.0f;
            #pragma unroll
            for (int d = 0; d < 16; ++d) lg += h[d] * v[d];
            float lj[10];
            #pragma unroll
            for (int j = 0; j < 10; ++j) lj[j] = __shfl(lg, base + j);
            float m = lj[0];
            #pragma unroll
            for (int j = 1; j < 10; ++j) m = fmaxf(m, lj[j]);
            float sum = 0.0f;
            #pragma unroll
            for (int j = 0; j < 10; ++j) sum += __expf(lj[j] - m);
            const float coef = __expf(lg - m) / sum;
            #pragma unroll
            for (int d = 0; d < 16; ++d) s_acc[d] += coef * h[d];
        }
    }
    if (PASS == 0) {
        #pragma unroll
        for (int d = 0; d < 16; ++d) s_acc[d] *= 0.1f;
    }
    if (valid) {
#if defined(__HIP_DEVICE_COMPILE__)
        #pragma unroll
        for (int d = 0; d < 16; ++d)
            unsafeAtomicAdd(&s_atomic[((size_t)b * 10 + c) * 16 + d], s_acc[d]);
#endif
    }
}

extern "C" void kernel_launch(void* const* d_in, const int* in_sizes, int n_in,
                              void* d_out, int out_size, void* d_ws, size_t ws_size,
                              hipStream_t stream)
{
    const float* u = (const float*)d_in[0];   // [512,1152,8]
    const float* W = (const float*)d_in[1];   // [1152,10,16,8]
    float* out = (float*)d_out;               // [512,10,16]

    float* v0 = (float*)d_ws;
    float* v1 = v0 + 81920;
    float* s0 = v1 + 81920;
    float* s1 = s0 + 81920;
    float* s2 = s1 + 81920;
    float* wt = s2 + 81920;                   // 1,474,560 f32 (5.9 MB)

    const size_t head   = (size_t)5 * 81920 * sizeof(float);          // 1.64 MB
    const size_t wtsz   = (size_t)1152 * 1280 * sizeof(float);        // 5.90 MB
    const size_t uh_b16 = (size_t)512 * 1152 * 160 * 2;               // 188.7 MB

    hipMemsetAsync(s0, 0, (size_t)3 * 81920 * sizeof(float), stream);

    dim3 blk(256);

    if (ws_size >= head + wtsz + uh_b16) {
        unsigned short* uhh = (unsigned short*)(wt + 1152 * 1280);
        transpose_W<<<1440, blk, 0, stream>>>((const float4*)W, (float4*)wt);
        produce_uhat_t<<<1024, blk, 0, stream>>>(u, wt, uhh, s0);
        squash_scale<<<20, blk, 0, stream>>>(s0, v0, 0.1f);
        route7<1><<<2048, blk, 0, stream>>>(uhh, v0, nullptr, s1);
        squash_scale<<<20, blk, 0, stream>>>(s1, v1, 1.0f);
        route7<2><<<2048, blk, 0, stream>>>(uhh, v0, v1, s2);
        squash_scale<<<20, blk, 0, stream>>>(s2, out, 1.0f);
    } else if (ws_size >= head + uh_b16) {
        unsigned short* uhh = (unsigned short*)wt;   // no W_t buffer
        produce_uhat_div<<<1024, blk, 0, stream>>>(u, W, uhh, s0);
        squash_scale<<<20, blk, 0, stream>>>(s0, v0, 0.1f);
        route7<1><<<2048, blk, 0, stream>>>(uhh, v0, nullptr, s1);
        squash_scale<<<20, blk, 0, stream>>>(s1, v1, 1.0f);
        route7<2><<<2048, blk, 0, stream>>>(uhh, v0, v1, s2);
        squash_scale<<<20, blk, 0, stream>>>(s2, out, 1.0f);
    } else {
        dim3 grid(48, 22);
        pass_fb<0><<<grid, blk, 0, stream>>>(u, W, nullptr, nullptr, s0);
        squash_scale<<<20, blk, 0, stream>>>(s0, v0, 1.0f);
        pass_fb<1><<<grid, blk, 0, stream>>>(u, W, v0, nullptr, s1);
        squash_scale<<<20, blk, 0, stream>>>(s1, v1, 1.0f);
        pass_fb<2><<<grid, blk, 0, stream>>>(u, W, v0, v1, s2);
        squash_scale<<<20, blk, 0, stream>>>(s2, out, 1.0f);
    }
}